// Round 5
// baseline (1413.604 us; speedup 1.0000x reference)
//
#include <hip/hip_runtime.h>
#include <hip/hip_bf16.h>

typedef _Float16 half8 __attribute__((ext_vector_type(8)));
typedef float floatx4 __attribute__((ext_vector_type(4)));

#define MFMA_F16(a, b, c) __builtin_amdgcn_mfma_f32_16x16x32_f16((a), (b), (c), 0, 0, 0)

// ---------------------------------------------------------------------------
// merged prep: 13 f32->f16 (opt transpose, scale) jobs + ctr init, one launch
// ---------------------------------------------------------------------------
struct PrepArgs {
  const float* src[13]; _Float16* dst[13];
  int In[13]; int On[13]; float scale[13]; int doT[13];
  int pre[14];
  int* ctr;
};

__global__ void prep_all_kernel(PrepArgs A) {
  if (blockIdx.x == 0 && threadIdx.x < 16) A.ctr[threadIdx.x] = 0;
  int j = 0;
  #pragma unroll 1
  while (j < 12 && (int)blockIdx.x >= A.pre[j + 1]) j++;
  int idx = (blockIdx.x - A.pre[j]) * 256 + threadIdx.x;
  int In = A.In[j], On = A.On[j];
  if (idx >= In * On) return;
  float v;
  if (A.doT[j]) { int o = idx / In, i = idx - o * In; v = A.src[j][i * On + o]; }
  else          { v = A.src[j][idx]; }
  A.dst[j][idx] = (_Float16)(v * A.scale[j]);
}

// ---------------------------------------------------------------------------
// phase 1: fused LN + dual GEMM, single pass. grid 1536, 256 threads.
// Each block: 128 rows x 256 outs (cols 0-127 -> k scaled, 128-255 -> v^T)
// ---------------------------------------------------------------------------
__global__ __launch_bounds__(256) void gemm_kv_kernel(
    const float* __restrict__ x, const float* __restrict__ lnw_g,
    const float* __restrict__ lnb_g, const _Float16* __restrict__ WT,
    _Float16* __restrict__ kout, _Float16* __restrict__ vTout) {
  __shared__ union {
    struct { _Float16 A[128][72]; _Float16 B[256][72]; } s;
    _Float16 C[128][136];
  } u;
  __shared__ float s_mean[128], s_rstd[128], s_red[256][2], s_lnw[256], s_lnb[256];

  const int tid = threadIdx.x;
  const int bx = blockIdx.x;
  const size_t r0 = (size_t)bx * 128;
  const int w = tid >> 6, lane = tid & 63, quad = lane >> 4, l15 = lane & 15;

  s_lnw[tid] = lnw_g[tid];
  s_lnb[tid] = lnb_g[tid];
  {
    int row = tid >> 1, half = tid & 1;
    const float* p = x + (r0 + row) * 256 + half * 128;
    float s = 0.f, sq = 0.f;
    for (int i = 0; i < 32; i++) {
      float4 d = ((const float4*)p)[i];
      s += d.x + d.y + d.z + d.w;
      sq += d.x * d.x + d.y * d.y + d.z * d.z + d.w * d.w;
    }
    s_red[tid][0] = s; s_red[tid][1] = sq;
  }
  __syncthreads();
  if (tid < 128) {
    float s  = s_red[2 * tid][0] + s_red[2 * tid + 1][0];
    float sq = s_red[2 * tid][1] + s_red[2 * tid + 1][1];
    float m = s * (1.f / 256.f);
    float v = sq * (1.f / 256.f) - m * m;
    s_mean[tid] = m; s_rstd[tid] = rsqrtf(v + 1e-5f);
  }

  floatx4 acc[2][16];
  for (int rt = 0; rt < 2; rt++)
    for (int ct = 0; ct < 16; ct++) acc[rt][ct] = (floatx4){0.f, 0.f, 0.f, 0.f};

  for (int c = 0; c < 4; c++) {
    __syncthreads();
    for (int i = 0; i < 4; i++) {      // A: 128 rows x 8 half8
      int gg = tid + 256 * i;
      int row = gg >> 3, c8 = gg & 7;
      int col0 = c * 64 + c8 * 8;
      const float* p = x + (r0 + row) * 256 + col0;
      float4 d0 = ((const float4*)p)[0];
      float4 d1 = ((const float4*)p)[1];
      float f[8] = {d0.x, d0.y, d0.z, d0.w, d1.x, d1.y, d1.z, d1.w};
      float m = s_mean[row], rs = s_rstd[row];
      half8 hv;
      #pragma unroll
      for (int j = 0; j < 8; j++)
        hv[j] = (_Float16)((f[j] - m) * rs * s_lnw[col0 + j] + s_lnb[col0 + j]);
      *(half8*)&u.s.A[row][c8 * 8] = hv;
    }
    for (int i = 0; i < 8; i++) {      // B: 256 rows x 8 half8
      int gg = tid + 256 * i;
      int row = gg >> 3, c8 = gg & 7;
      int col0 = c * 64 + c8 * 8;
      *(half8*)&u.s.B[row][c8 * 8] = *(const half8*)(WT + (size_t)row * 256 + col0);
    }
    __syncthreads();
    #pragma unroll
    for (int ks = 0; ks < 2; ks++) {
      half8 af[2];
      af[0] = *(const half8*)&u.s.A[(2 * w) * 16 + l15][ks * 32 + quad * 8];
      af[1] = *(const half8*)&u.s.A[(2 * w + 1) * 16 + l15][ks * 32 + quad * 8];
      #pragma unroll
      for (int ct = 0; ct < 16; ct++) {
        half8 bf = *(const half8*)&u.s.B[ct * 16 + l15][ks * 32 + quad * 8];
        acc[0][ct] = MFMA_F16(af[0], bf, acc[0][ct]);
        acc[1][ct] = MFMA_F16(af[1], bf, acc[1][ct]);
      }
    }
  }

  // k epilogue (ct 0-7): direct coalesced store
  for (int rt = 0; rt < 2; rt++)
    for (int ct = 0; ct < 8; ct++)
      #pragma unroll
      for (int r = 0; r < 4; r++) {
        size_t row = r0 + (2 * w + rt) * 16 + quad * 4 + r;
        kout[row * 128 + ct * 16 + l15] = (_Float16)acc[rt][ct][r];
      }
  // v epilogue (ct 8-15): LDS transpose -> vT
  __syncthreads();
  for (int rt = 0; rt < 2; rt++)
    for (int ct = 8; ct < 16; ct++)
      #pragma unroll
      for (int r = 0; r < 4; r++)
        u.C[(2 * w + rt) * 16 + quad * 4 + r][(ct - 8) * 16 + l15] = (_Float16)acc[rt][ct][r];
  __syncthreads();
  const size_t bt = (size_t)(bx >> 3);
  const int n0loc = (bx & 7) * 128;
  int s = tid >> 1, hf = tid & 1;
  for (int j = 0; j < 8; j++) {
    int nb = hf * 64 + j * 8;
    half8 tmp;
    #pragma unroll
    for (int e = 0; e < 8; e++) tmp[e] = u.C[nb + e][s];
    *(half8*)(vTout + (bt * 128 + s) * 1024 + n0loc + nb) = tmp;
  }
}

// ---------------------------------------------------------------------------
// phase 2: grid 256 (= 16 batches x 16 n-groups), 512 threads (8 waves).
// Each block owns 64 n-rows; k/v slice LDS-resident per t. GRU fused into
// registers (gh precomputed before the cross-block barrier).
// ---------------------------------------------------------------------------
struct P2Args {
  const _Float16 *kbuf, *vT;
  const _Float16 *WqT, *Wih, *Whh, *W1T, *W2T;
  const _Float16 *pQT, *pKT, *pVT, *pOT, *pF1T, *pF2T;
  const float *noise, *mu, *lsig;
  const float *lnsw, *lnsb, *lnmw, *lnmb;
  const float *bih, *bhh, *mb1, *mb2;
  const float *pl1w, *pl1b, *pl2w, *pl2b, *fb1, *fb2, *plfw, *plfb;
  float *out_slots, *out_attn;
  float *upd_p;   // [2][16][16][1024]
  float *col_p;   // [2][16][16][8]
  float *vs_p;    // [16][16][128]
  int   *ctr;     // [16]
};

struct SH {
  _Float16 k_lds[64][136];    // [n_local][s]
  _Float16 v_lds[128][72];    // [s][n_local]
  float slots[8][128];
  _Float16 a16[16][136];
  _Float16 h16[16][136];
  union {
    struct { _Float16 qT[16][136]; _Float16 attnT[16][72]; } sa;
    struct { _Float16 m16[16][264]; } mlp;
    struct { float qh[8][128]; float kh[8][128]; float vh[8][128]; float sc[4][8][8]; } mha;
    struct { _Float16 f16[16][520]; } ffn;
  } u;
  float colsum[8];
  float vsum[128];
  float bih[384], bhh[384], mb1[256], mb2[128], fb1[512], fb2[128];
  float lnsw[128], lnsb[128], lnmw[128], lnmb[128];
  float pl1w[128], pl1b[128], pl2w[128], pl2b[128], plfw[128], plfb[128];
};

__device__ __forceinline__ void group_barrier(int* ctr, int target) {
  __syncthreads();
  if (threadIdx.x == 0) {
    __hip_atomic_fetch_add(ctr, 1, __ATOMIC_ACQ_REL, __HIP_MEMORY_SCOPE_AGENT);
    while (__hip_atomic_load(ctr, __ATOMIC_ACQUIRE, __HIP_MEMORY_SCOPE_AGENT) < target)
      __builtin_amdgcn_s_sleep(1);
  }
  __syncthreads();
}

// LN of slots row w -> a16 row w (8 waves; rows 8-15 stay zero from init)
__device__ __forceinline__ void ln_to_a16(SH* sh, const float* wv, const float* bv,
                                          int w, int lane) {
  float x0 = sh->slots[w][lane], x1 = sh->slots[w][lane + 64];
  float s = x0 + x1, sq = x0 * x0 + x1 * x1;
  #pragma unroll
  for (int m = 1; m < 64; m <<= 1) { s += __shfl_xor(s, m); sq += __shfl_xor(sq, m); }
  float mn = s * 0.0078125f;
  float vr = sq * 0.0078125f - mn * mn;
  float rs = rsqrtf(vr + 1e-5f);
  sh->a16[w][lane]      = (_Float16)((x0 - mn) * rs * wv[lane]      + bv[lane]);
  sh->a16[w][lane + 64] = (_Float16)((x1 - mn) * rs * wv[lane + 64] + bv[lane + 64]);
}

__global__ __launch_bounds__(512) void slot_attn_kernel(P2Args P) {
  __shared__ SH sh;
  const int tid = threadIdx.x;
  const int w = tid >> 6, lane = tid & 63, quad = lane >> 4, l15 = lane & 15;
  const int b = blockIdx.x & 15;       // batch
  const int g = blockIdx.x >> 4;       // n-group 0..15; b+16k -> same XCD
  const int n0 = g * 64;
  int* ctrb = P.ctr + b;
  int bar_phase = 0;

  for (int i = tid; i < 384; i += 512) { sh.bih[i] = P.bih[i]; sh.bhh[i] = P.bhh[i]; }
  if (tid < 256) sh.mb1[tid] = P.mb1[tid];
  sh.fb1[tid] = P.fb1[tid];
  if (tid < 128) {
    sh.mb2[tid]  = P.mb2[tid];  sh.fb2[tid]  = P.fb2[tid];
    sh.lnsw[tid] = P.lnsw[tid]; sh.lnsb[tid] = P.lnsb[tid];
    sh.lnmw[tid] = P.lnmw[tid]; sh.lnmb[tid] = P.lnmb[tid];
    sh.pl1w[tid] = P.pl1w[tid]; sh.pl1b[tid] = P.pl1b[tid];
    sh.pl2w[tid] = P.pl2w[tid]; sh.pl2b[tid] = P.pl2b[tid];
    sh.plfw[tid] = P.plfw[tid]; sh.plfb[tid] = P.plfb[tid];
  }
  for (int i = tid; i < 1024; i += 512) {
    int kk = i >> 7, s = i & 127;
    sh.slots[kk][s] = P.mu[s] + expf(P.lsig[s]) * P.noise[(b * 8 + kk) * 128 + s];
  }
  {  // zero a16/h16 rows 8-15 once (never written again)
    _Float16* pa = &sh.a16[8][0];
    _Float16* ph = &sh.h16[8][0];
    for (int i = tid; i < 8 * 136; i += 512) { pa[i] = (_Float16)0.f; ph[i] = (_Float16)0.f; }
  }
  __syncthreads();

  for (int t = 0; t < 12; t++) {
    const _Float16* kt = P.kbuf + ((size_t)(b * 12 + t)) * 1024 * 128 + (size_t)n0 * 128;
    const _Float16* vt = P.vT   + ((size_t)(b * 12 + t)) * 128 * 1024 + n0;
    // ---- S0: stage k/v slices; zero vsum/colsum
    for (int e = tid; e < 1024; e += 512) {
      int row = e >> 4, c8 = (e & 15) * 8;   // k: 64 rows x 16 half8
      *(half8*)&sh.k_lds[row][c8] = *(const half8*)(kt + (size_t)row * 128 + c8);
    }
    for (int e = tid; e < 1024; e += 512) {
      int row = e >> 3, c8 = (e & 7) * 8;    // v: 128 rows x 8 half8
      *(half8*)&sh.v_lds[row][c8] = *(const half8*)(vt + (size_t)row * 1024 + c8);
    }
    if (tid < 128) sh.vsum[tid] = 0.f;
    if (tid < 8) sh.colsum[tid] = 0.f;
    __syncthreads();
    // ---- S0b: vsum partial + it0 LN + h16
    {
      int s = tid >> 2, j = tid & 3;
      half8 h0 = *(const half8*)&sh.v_lds[s][j * 16];
      half8 h1 = *(const half8*)&sh.v_lds[s][j * 16 + 8];
      float a = 0.f;
      #pragma unroll
      for (int e = 0; e < 8; e++) a += (float)h0[e] + (float)h1[e];
      atomicAdd(&sh.vsum[s], a);
    }
    {
      float x0 = sh.slots[w][lane], x1 = sh.slots[w][lane + 64];
      sh.h16[w][lane] = (_Float16)x0; sh.h16[w][lane + 64] = (_Float16)x1;
      float s = x0 + x1, sq = x0 * x0 + x1 * x1;
      #pragma unroll
      for (int m = 1; m < 64; m <<= 1) { s += __shfl_xor(s, m); sq += __shfl_xor(sq, m); }
      float mn = s * 0.0078125f;
      float vr = sq * 0.0078125f - mn * mn;
      float rs = rsqrtf(vr + 1e-5f);
      sh.a16[w][lane]      = (_Float16)((x0 - mn) * rs * sh.lnsw[lane]      + sh.lnsb[lane]);
      sh.a16[w][lane + 64] = (_Float16)((x1 - mn) * rs * sh.lnsw[lane + 64] + sh.lnsb[lane + 64]);
    }
    __syncthreads();

    for (int it = 0; it < 3; it++) {
      const int par = (t * 3 + it) & 1;
      float* updg = P.upd_p + ((size_t)(par * 16 + b) * 16 + g) * 1024;
      float* colg = P.col_p + ((size_t)(par * 16 + b) * 16 + g) * 8;
      if (it > 0) {
        // ---- S1: LN(slots)+h16+zero colsum
        float x0 = sh.slots[w][lane], x1 = sh.slots[w][lane + 64];
        sh.h16[w][lane] = (_Float16)x0; sh.h16[w][lane + 64] = (_Float16)x1;
        float s = x0 + x1, sq = x0 * x0 + x1 * x1;
        #pragma unroll
        for (int m = 1; m < 64; m <<= 1) { s += __shfl_xor(s, m); sq += __shfl_xor(sq, m); }
        float mn = s * 0.0078125f;
        float vr = sq * 0.0078125f - mn * mn;
        float rs = rsqrtf(vr + 1e-5f);
        sh.a16[w][lane]      = (_Float16)((x0 - mn) * rs * sh.lnsw[lane]      + sh.lnsb[lane]);
        sh.a16[w][lane + 64] = (_Float16)((x1 - mn) * rs * sh.lnsw[lane + 64] + sh.lnsb[lane + 64]);
        if (tid < 8) sh.colsum[tid] = 0.f;
        __syncthreads();
      }
      // ---- S2: q GEMM + gh triple (register-resident across barrier)
      floatx4 ghr = (floatx4){0.f,0.f,0.f,0.f}, ghz = ghr, ghn = ghr;
      {
        floatx4 aq = (floatx4){0.f,0.f,0.f,0.f};
        const _Float16* ar = &sh.a16[l15][quad * 8];
        const _Float16* hr = &sh.h16[l15][quad * 8];
        const _Float16* bq = P.WqT + (size_t)(w * 16 + l15) * 128 + quad * 8;
        const _Float16* br_ = P.Whh + (size_t)(w * 16 + l15) * 128 + quad * 8;
        const _Float16* bz = P.Whh + (size_t)((w + 8) * 16 + l15) * 128 + quad * 8;
        const _Float16* bn = P.Whh + (size_t)((w + 16) * 16 + l15) * 128 + quad * 8;
        #pragma unroll
        for (int ks = 0; ks < 4; ks++) {
          half8 hf = *(const half8*)(hr + ks * 32);
          aq  = MFMA_F16(*(const half8*)(ar + ks * 32), *(const half8*)(bq + ks * 32), aq);
          ghr = MFMA_F16(hf, *(const half8*)(br_ + ks * 32), ghr);
          ghz = MFMA_F16(hf, *(const half8*)(bz + ks * 32), ghz);
          ghn = MFMA_F16(hf, *(const half8*)(bn + ks * 32), ghn);
        }
        #pragma unroll
        for (int r = 0; r < 4; r++)
          sh.u.sa.qT[quad * 4 + r][w * 16 + l15] = (_Float16)aq[r];
      }
      if (it == 0 && tid < 128)
        __hip_atomic_store(&P.vs_p[(b * 16 + g) * 128 + tid], sh.vsum[tid],
                           __ATOMIC_RELAXED, __HIP_MEMORY_SCOPE_AGENT);
      __syncthreads();
      // ---- S3: logits (64 local n) + softmax over slots (waves 0-3)
      if (w < 4) {
        int nloc0 = w * 16;
        floatx4 acc = (floatx4){0.f,0.f,0.f,0.f};
        const _Float16* ar = &sh.k_lds[nloc0 + l15][quad * 8];
        const _Float16* br = &sh.u.sa.qT[l15][quad * 8];
        #pragma unroll
        for (int ks = 0; ks < 4; ks++)
          acc = MFMA_F16(*(const half8*)(ar + ks * 32), *(const half8*)(br + ks * 32), acc);
        float cs = 0.f;
        #pragma unroll
        for (int r = 0; r < 4; r++) {
          float v = (l15 < 8) ? acc[r] : -3.0e38f;
          float mx = v;
          mx = fmaxf(mx, __shfl_xor(mx, 1, 16));
          mx = fmaxf(mx, __shfl_xor(mx, 2, 16));
          mx = fmaxf(mx, __shfl_xor(mx, 4, 16));
          mx = fmaxf(mx, __shfl_xor(mx, 8, 16));
          float pv = (l15 < 8) ? expf(v - mx) : 0.f;
          float ss = pv;
          ss += __shfl_xor(ss, 1, 16); ss += __shfl_xor(ss, 2, 16);
          ss += __shfl_xor(ss, 4, 16); ss += __shfl_xor(ss, 8, 16);
          float pn = pv / ss;
          cs += pn;
          int nloc = nloc0 + quad * 4 + r;
          sh.u.sa.attnT[l15][nloc] = (_Float16)pn;
          if (it == 2 && l15 < 8)
            P.out_attn[((size_t)(b * 12 + t) * 1024 + n0 + nloc) * 8 + l15] = pn;
        }
        cs += __shfl_xor(cs, 16); cs += __shfl_xor(cs, 32);
        if (lane < 8) atomicAdd(&sh.colsum[lane], cs);
      }
      __syncthreads();
      // ---- S4: partial updates = P^T @ v (K=64) -> global; colsum -> global
      {
        floatx4 acc = (floatx4){0.f,0.f,0.f,0.f};
        const _Float16* ar = &sh.u.sa.attnT[l15][quad * 8];
        const _Float16* br = &sh.v_lds[w * 16 + l15][quad * 8];
        #pragma unroll
        for (int ks = 0; ks < 2; ks++)
          acc = MFMA_F16(*(const half8*)(ar + ks * 32), *(const half8*)(br + ks * 32), acc);
        int scol = w * 16 + l15;
        if (quad < 2) {
          #pragma unroll
          for (int r = 0; r < 4; r++)
            __hip_atomic_store(&updg[(quad * 4 + r) * 128 + scol], acc[r],
                               __ATOMIC_RELAXED, __HIP_MEMORY_SCOPE_AGENT);
        }
      }
      if (tid < 8)
        __hip_atomic_store(&colg[tid], sh.colsum[tid],
                           __ATOMIC_RELAXED, __HIP_MEMORY_SCOPE_AGENT);
      bar_phase++;
      group_barrier(ctrb, 16 * bar_phase);
      // ---- S5: reduce 16 partials; fold eps renorm -> a16
      {
        float sum[2];
        #pragma unroll
        for (int p = 0; p < 2; p++) {
          int i = tid + p * 512;
          int slot = i >> 7, scol = i & 127;
          const float* up = P.upd_p + (size_t)(par * 16 + b) * 16 * 1024 + slot * 128 + scol;
          float s = 0.f;
          #pragma unroll
          for (int gg = 0; gg < 16; gg++)
            s += __hip_atomic_load((float*)(up + gg * 1024),
                                   __ATOMIC_RELAXED, __HIP_MEMORY_SCOPE_AGENT);
          sum[p] = s;
        }
        float csum = 0.f;
        if (tid < 8) {
          const float* cp = P.col_p + (size_t)(par * 16 + b) * 16 * 8 + tid;
          #pragma unroll
          for (int gg = 0; gg < 16; gg++)
            csum += __hip_atomic_load((float*)(cp + gg * 8),
                                      __ATOMIC_RELAXED, __HIP_MEMORY_SCOPE_AGENT);
        }
        float vtot = 0.f;
        if (it == 0 && tid < 128) {
          const float* vp = P.vs_p + b * 16 * 128 + tid;
          #pragma unroll
          for (int gg = 0; gg < 16; gg++)
            vtot += __hip_atomic_load((float*)(vp + gg * 128),
                                      __ATOMIC_RELAXED, __HIP_MEMORY_SCOPE_AGENT);
        }
        if (tid < 8) sh.colsum[tid] = csum;
        if (it == 0 && tid < 128) sh.vsum[tid] = vtot;
        __syncthreads();
        #pragma unroll
        for (int p = 0; p < 2; p++) {
          int i = tid + p * 512;
          int slot = i >> 7, scol = i & 127;
          float upd = (sum[p] + 1e-8f * sh.vsum[scol]) / (sh.colsum[slot] + 1024.f * 1e-8f);
          sh.a16[slot][scol] = (_Float16)upd;
        }
      }
      __syncthreads();
      // ---- S6: fused GRU (gi triple in-register + held gh) -> slots
      {
        floatx4 gir = (floatx4){0.f,0.f,0.f,0.f}, giz = gir, gin = gir;
        const _Float16* ar = &sh.a16[l15][quad * 8];
        const _Float16* br_ = P.Wih + (size_t)(w * 16 + l15) * 128 + quad * 8;
        const _Float16* bz = P.Wih + (size_t)((w + 8) * 16 + l15) * 128 + quad * 8;
        const _Float16* bn = P.Wih + (size_t)((w + 16) * 16 + l15) * 128 + quad * 8;
        #pragma unroll
        for (int ks = 0; ks < 4; ks++) {
          half8 af = *(const half8*)(ar + ks * 32);
          gir = MFMA_F16(af, *(const half8*)(br_ + ks * 32), gir);
          giz = MFMA_F16(af, *(const half8*)(bz + ks * 32), giz);
          gin = MFMA_F16(af, *(const half8*)(bn + ks * 32), gin);
        }
        int c = w * 16 + l15;
        if (quad < 2) {
          float b_r = sh.bih[c],       h_r = sh.bhh[c];
          float b_z = sh.bih[128 + c], h_z = sh.bhh[128 + c];
          float b_n = sh.bih[256 + c], h_n = sh.bhh[256 + c];
          #pragma unroll
          for (int r = 0; r < 4; r++) {
            int slot = quad * 4 + r;
            float grv = gir[r] + b_r + ghr[r] + h_r;
            float gzv = giz[r] + b_z + ghz[r] + h_z;
            float rg = 1.f / (1.f + expf(-grv));
            float zg = 1.f / (1.f + expf(-gzv));
            float ng = tanhf(gin[r] + b_n + rg * (ghn[r] + h_n));
            float h = sh.slots[slot][c];
            sh.slots[slot][c] = (1.f - zg) * ng + zg * h;
          }
        }
      }
      __syncthreads();
      // ---- S7-S9: residual MLP (iters 0,1)
      if (it < 2) {
        ln_to_a16(&sh, sh.lnmw, sh.lnmb, w, lane);
        __syncthreads();
        for (int ct = w; ct < 16; ct += 8) {
          floatx4 acc = (floatx4){0.f,0.f,0.f,0.f};
          const _Float16* ar = &sh.a16[l15][quad * 8];
          const _Float16* br = P.W1T + (size_t)(ct * 16 + l15) * 128 + quad * 8;
          #pragma unroll
          for (int ks = 0; ks < 4; ks++)
            acc = MFMA_F16(*(const half8*)(ar + ks * 32), *(const half8*)(br + ks * 32), acc);
          int col = ct * 16 + l15;
          #pragma unroll
          for (int r = 0; r < 4; r++) {
            int slot = quad * 4 + r;
            sh.u.mlp.m16[slot][col] = (slot < 8) ? (_Float16)fmaxf(acc[r] + sh.mb1[col], 0.f)
                                                 : (_Float16)0.f;
          }
        }
        __syncthreads();
        {
          floatx4 acc = (floatx4){0.f,0.f,0.f,0.f};
          const _Float16* ar = &sh.u.mlp.m16[l15][quad * 8];
          const _Float16* br = P.W2T + (size_t)(w * 16 + l15) * 256 + quad * 8;
          #pragma unroll
          for (int ks = 0; ks < 8; ks++)
            acc = MFMA_F16(*(const half8*)(ar + ks * 32), *(const half8*)(br + ks * 32), acc);
          int col = w * 16 + l15;
          if (quad < 2) {
            #pragma unroll
            for (int r = 0; r < 4; r++)
              sh.slots[quad * 4 + r][col] += acc[r] + sh.mb2[col];
          }
        }
        __syncthreads();
      }
    } // it

    if (g == 0) {
      for (int i = tid; i < 1024; i += 512) {
        int kk = i >> 7, s = i & 127;
        P.out_slots[((size_t)(b * 12 + t) * 8 + kk) * 128 + s] = sh.slots[kk][s];
      }
    }
    // ---- predictor (redundant, identical in all 16 blocks)
    ln_to_a16(&sh, sh.pl1w, sh.pl1b, w, lane);
    __syncthreads();
    {  // qkv projections: wave w does q,k,v tile ct=w
      floatx4 aq = (floatx4){0.f,0.f,0.f,0.f}, ak = aq, av = aq;
      const _Float16* ar = &sh.a16[l15][quad * 8];
      const _Float16* bq = P.pQT + (size_t)(w * 16 + l15) * 128 + quad * 8;
      const _Float16* bk = P.pKT + (size_t)(w * 16 + l15) * 128 + quad * 8;
      const _Float16* bv = P.pVT + (size_t)(w * 16 + l15) * 128 + quad * 8;
      #pragma unroll
      for (int ks = 0; ks < 4; ks++) {
        half8 af = *(const half8*)(ar + ks * 32);
        aq = MFMA_F16(af, *(const half8*)(bq + ks * 32), aq);
        ak = MFMA_F16(af, *(const half8*)(bk + ks * 32), ak);
        av = MFMA_F16(af, *(const half8*)(bv + ks * 32), av);
      }
      int col = w * 16 + l15;
      if (quad < 2) {
        #pragma unroll
        for (int r = 0; r < 4; r++) {
          int slot = quad * 4 + r;
          sh.u.mha.qh[slot][col] = aq[r] * 0.17677669529663687f;
          sh.u.mha.kh[slot][col] = ak[r];
          sh.u.mha.vh[slot][col] = av[r];
        }
      }
    }
    __syncthreads();
    if (tid < 256) {
      int h = tid >> 6, a = (tid >> 3) & 7, b2 = tid & 7;
      const float* qr = &sh.u.mha.qh[a][h * 32];
      const float* kr = &sh.u.mha.kh[b2][h * 32];
      float s = 0.f;
      #pragma unroll
      for (int d = 0; d < 32; d++) s += qr[d] * kr[d];
      sh.u.mha.sc[h][a][b2] = s;
    }
    __syncthreads();
    if (tid < 32) {
      int h = tid >> 3, a = tid & 7;
      float* p = sh.u.mha.sc[h][a];
      float mx = p[0];
      #pragma unroll
      for (int j = 1; j < 8; j++) mx = fmaxf(mx, p[j]);
      float e[8]; float ssum = 0.f;
      #pragma unroll
      for (int j = 0; j < 8; j++) { e[j] = expf(p[j] - mx); ssum += e[j]; }
      float inv = 1.f / ssum;
      #pragma unroll
      for (int j = 0; j < 8; j++) p[j] = e[j] * inv;
    }
    __syncthreads();
    for (int i = tid; i < 1024; i += 512) {   // o = a @ v -> a16 rows 0-7
      int a = i >> 7, col = i & 127, h = col >> 5;
      float acc = 0.f;
      #pragma unroll
      for (int b2 = 0; b2 < 8; b2++) acc += sh.u.mha.sc[h][a][b2] * sh.u.mha.vh[b2][col];
      sh.a16[a][col] = (_Float16)acc;
    }
    __syncthreads();
    {  // s += o @ Wo
      floatx4 acc = (floatx4){0.f,0.f,0.f,0.f};
      const _Float16* ar = &sh.a16[l15][quad * 8];
      const _Float16* br = P.pOT + (size_t)(w * 16 + l15) * 128 + quad * 8;
      #pragma unroll
      for (int ks = 0; ks < 4; ks++)
        acc = MFMA_F16(*(const half8*)(ar + ks * 32), *(const half8*)(br + ks * 32), acc);
      int col = w * 16 + l15;
      if (quad < 2) {
        #pragma unroll
        for (int r = 0; r < 4; r++)
          sh.slots[quad * 4 + r][col] += acc[r];
      }
    }
    __syncthreads();
    ln_to_a16(&sh, sh.pl2w, sh.pl2b, w, lane);
    __syncthreads();
    for (int ct = w; ct < 32; ct += 8) {   // FFN1 + relu
      floatx4 acc = (floatx4){0.f,0.f,0.f,0.f};
      const _Float16* ar = &sh.a16[l15][quad * 8];
      const _Float16* br = P.pF1T + (size_t)(ct * 16 + l15) * 128 + quad * 8;
      #pragma unroll
      for (int ks = 0; ks < 4; ks++)
        acc = MFMA_F16(*(const half8*)(ar + ks * 32), *(const half8*)(br + ks * 32), acc);
      int col = ct * 16 + l15;
      #pragma unroll
      for (int r = 0; r < 4; r++) {
        int slot = quad * 4 + r;
        sh.u.ffn.f16[slot][col] = (slot < 8) ? (_Float16)fmaxf(acc[r] + sh.fb1[col], 0.f)
                                             : (_Float16)0.f;
      }
    }
    __syncthreads();
    {  // FFN2 + residual
      floatx4 acc = (floatx4){0.f,0.f,0.f,0.f};
      const _Float16* ar = &sh.u.ffn.f16[l15][quad * 8];
      const _Float16* br = P.pF2T + (size_t)(w * 16 + l15) * 512 + quad * 8;
      #pragma unroll 4
      for (int ks = 0; ks < 16; ks++)
        acc = MFMA_F16(*(const half8*)(ar + ks * 32), *(const half8*)(br + ks * 32), acc);
      int col = w * 16 + l15;
      if (quad < 2) {
        #pragma unroll
        for (int r = 0; r < 4; r++)
          sh.slots[quad * 4 + r][col] += acc[r] + sh.fb2[col];
      }
    }
    __syncthreads();
    {  // final LN in place
      float x0 = sh.slots[w][lane], x1 = sh.slots[w][lane + 64];
      float s = x0 + x1, sq = x0 * x0 + x1 * x1;
      #pragma unroll
      for (int m = 1; m < 64; m <<= 1) { s += __shfl_xor(s, m); sq += __shfl_xor(sq, m); }
      float mn = s * 0.0078125f;
      float vr = sq * 0.0078125f - mn * mn;
      float rs = rsqrtf(vr + 1e-5f);
      sh.slots[w][lane]      = (x0 - mn) * rs * sh.plfw[lane]      + sh.plfb[lane];
      sh.slots[w][lane + 64] = (x1 - mn) * rs * sh.plfw[lane + 64] + sh.plfb[lane + 64];
    }
    __syncthreads();
  } // t
}

// ---------------------------------------------------------------------------
extern "C" void kernel_launch(void* const* d_in, const int* in_sizes, int n_in,
                              void* d_out, int out_size, void* d_ws, size_t ws_size,
                              hipStream_t stream) {
  const float* inp   = (const float*)d_in[0];
  const float* noise = (const float*)d_in[1];
  const float* mu    = (const float*)d_in[2];
  const float* lsig  = (const float*)d_in[3];
  const float* lniw  = (const float*)d_in[4];
  const float* lnib  = (const float*)d_in[5];
  const float* lnsw  = (const float*)d_in[6];
  const float* lnsb  = (const float*)d_in[7];
  const float* lnmw  = (const float*)d_in[8];
  const float* lnmb  = (const float*)d_in[9];
  const float* Wq    = (const float*)d_in[10];
  const float* Wk    = (const float*)d_in[11];
  const float* Wv    = (const float*)d_in[12];
  const float* gWih  = (const float*)d_in[13];
  const float* gWhh  = (const float*)d_in[14];
  const float* gbih  = (const float*)d_in[15];
  const float* gbhh  = (const float*)d_in[16];
  const float* mW1   = (const float*)d_in[17];
  const float* mb1   = (const float*)d_in[18];
  const float* mW2   = (const float*)d_in[19];
  const float* mb2   = (const float*)d_in[20];
  const float* pl1w  = (const float*)d_in[21];
  const float* pl1b  = (const float*)d_in[22];
  const float* pWq   = (const float*)d_in[23];
  const float* pWk   = (const float*)d_in[24];
  const float* pWv   = (const float*)d_in[25];
  const float* pWo   = (const float*)d_in[26];
  const float* pl2w  = (const float*)d_in[27];
  const float* pl2b  = (const float*)d_in[28];
  const float* pf1   = (const float*)d_in[29];
  const float* pfb1  = (const float*)d_in[30];
  const float* pf2   = (const float*)d_in[31];
  const float* pfb2  = (const float*)d_in[32];
  const float* plfw  = (const float*)d_in[33];
  const float* plfb  = (const float*)d_in[34];

  _Float16* p   = (_Float16*)d_ws;
  _Float16* kbuf = p;  p += 25165824;
  _Float16* vT   = p;  p += 25165824;
  _Float16* WT   = p;  p += 65536;
  _Float16* WqT  = p;  p += 16384;
  _Float16* Wih  = p;  p += 49152;
  _Float16* Whh  = p;  p += 49152;
  _Float16* W1T  = p;  p += 32768;
  _Float16* W2T  = p;  p += 32768;
  _Float16* pQT  = p;  p += 16384;
  _Float16* pKT  = p;  p += 16384;
  _Float16* pVT  = p;  p += 16384;
  _Float16* pOT  = p;  p += 16384;
  _Float16* pF1T = p;  p += 65536;
  _Float16* pF2T = p;  p += 65536;
  float* fb   = (float*)p;
  float* upd_p = fb;  fb += 2 * 16 * 16 * 1024;  // 524288
  float* col_p = fb;  fb += 2 * 16 * 16 * 8;     // 4096
  float* vs_p  = fb;  fb += 16 * 16 * 128;       // 32768
  int*   ctr   = (int*)fb;                       // 16

  const float kscale = 0.08838834764831845f;  // S^-0.5, S=128

  PrepArgs pa;
  const float* srcs[13] = {Wk, Wv, Wq, gWih, gWhh, mW1, mW2, pWq, pWk, pWv, pWo, pf1, pf2};
  _Float16* dsts[13] = {WT, WT + 32768, WqT, Wih, Whh, W1T, W2T, pQT, pKT, pVT, pOT, pF1T, pF2T};
  int Ins[13]  = {256, 256, 128, 49152, 49152, 128, 256, 128, 128, 128, 128, 128, 512};
  int Ons[13]  = {128, 128, 128, 1,     1,     256, 128, 128, 128, 128, 128, 512, 128};
  float scs[13] = {kscale, 1.f, 1.f, 1.f, 1.f, 1.f, 1.f, 1.f, 1.f, 1.f, 1.f, 1.f, 1.f};
  int dts[13]  = {1, 1, 1, 0, 0, 1, 1, 1, 1, 1, 1, 1, 1};
  int total = 0;
  for (int j = 0; j < 13; j++) {
    pa.src[j] = srcs[j]; pa.dst[j] = dsts[j];
    pa.In[j] = Ins[j]; pa.On[j] = Ons[j]; pa.scale[j] = scs[j]; pa.doT[j] = dts[j];
    pa.pre[j] = total;
    total += (Ins[j] * Ons[j] + 255) / 256;
  }
  pa.pre[13] = total;
  pa.ctr = ctr;
  prep_all_kernel<<<total, 256, 0, stream>>>(pa);

  gemm_kv_kernel<<<1536, 256, 0, stream>>>(inp, lniw, lnib, WT, kbuf, vT);

  P2Args a;
  a.kbuf = kbuf; a.vT = vT;
  a.WqT = WqT; a.Wih = Wih; a.Whh = Whh; a.W1T = W1T; a.W2T = W2T;
  a.pQT = pQT; a.pKT = pKT; a.pVT = pVT; a.pOT = pOT; a.pF1T = pF1T; a.pF2T = pF2T;
  a.noise = noise; a.mu = mu; a.lsig = lsig;
  a.lnsw = lnsw; a.lnsb = lnsb; a.lnmw = lnmw; a.lnmb = lnmb;
  a.bih = gbih; a.bhh = gbhh; a.mb1 = mb1; a.mb2 = mb2;
  a.pl1w = pl1w; a.pl1b = pl1b; a.pl2w = pl2w; a.pl2b = pl2b;
  a.fb1 = pfb1; a.fb2 = pfb2; a.plfw = plfw; a.plfb = plfb;
  a.out_slots = (float*)d_out;
  a.out_attn  = (float*)d_out + 196608;
  a.upd_p = upd_p; a.col_p = col_p; a.vs_p = vs_p; a.ctr = ctr;

  slot_attn_kernel<<<256, 512, 0, stream>>>(a);
}